// Round 11
// baseline (884.348 us; speedup 1.0000x reference)
//
#include <hip/hip_runtime.h>

#define NN 50000
#define NE 800000
#define EPSf 1e-5f

typedef _Float16 half8 __attribute__((ext_vector_type(8)));
typedef _Float16 half4v __attribute__((ext_vector_type(4)));
typedef float f32x4 __attribute__((ext_vector_type(4)));

#define HA_STRIDE 72    // halves: 64 + 8 pad (144B rows)
#define WB_STRIDE 72    // halves: 64 + 8 pad (one 64x64 W panel)

// ================= graph prep =================
__global__ void deg_hist_kernel(const int* __restrict__ row, const int* __restrict__ col,
                                const float* __restrict__ ew,
                                float* __restrict__ deg, int* __restrict__ cnt) {
  int e = blockIdx.x * 256 + threadIdx.x;
  if (e >= NE) return;
  int c = col[e];
  unsafeAtomicAdd(&deg[c], ew[e]);
  atomicAdd(&cnt[c], 1);
}

__global__ void scan1(int* __restrict__ cnt, int* __restrict__ aux) {
  __shared__ int ls[256];
  int t = threadIdx.x, idx = blockIdx.x * 256 + t;
  int v = (idx < NN) ? cnt[idx] : 0;
  ls[t] = v;
  __syncthreads();
  for (int o = 1; o < 256; o <<= 1) {
    int u = (t >= o) ? ls[t - o] : 0;
    __syncthreads();
    ls[t] += u;
    __syncthreads();
  }
  if (idx < NN) cnt[idx] = ls[t] - v;
  if (t == 255) aux[blockIdx.x] = ls[255];
}

__global__ void scan2(int* __restrict__ aux, int nb) {
  __shared__ int ls[256];
  int t = threadIdx.x;
  int v = (t < nb) ? aux[t] : 0;
  ls[t] = v;
  __syncthreads();
  for (int o = 1; o < 256; o <<= 1) {
    int u = (t >= o) ? ls[t - o] : 0;
    __syncthreads();
    ls[t] += u;
    __syncthreads();
  }
  if (t < nb) aux[t] = ls[t] - v;
}

__global__ void scan3(int* __restrict__ cnt, const int* __restrict__ aux) {
  int idx = blockIdx.x * 256 + threadIdx.x;
  if (idx < NN) cnt[idx] += aux[idx >> 8];
}

// scatter with inline symmetric normalization (dinv folded in)
__global__ void scatter_kernel(const int* __restrict__ row, const int* __restrict__ col,
                               const float* __restrict__ ew, const float* __restrict__ deg,
                               int* __restrict__ rowptr, int2* __restrict__ pme) {
  int e = blockIdx.x * 256 + threadIdx.x;
  if (e >= NE) return;
  int r = row[e], c = col[e];
  float dr = deg[r], dc = deg[c];
  float ir = dr > 0.f ? rsqrtf(dr) : 0.f;
  float ic = dc > 0.f ? rsqrtf(dc) : 0.f;
  float w = ir * ew[e] * ic;
  int p = atomicAdd(&rowptr[c], 1);
  pme[p] = make_int2(r, __float_as_int(w));
}

// convert + transpose ALL MFMA weights to f16 once.
__global__ void cvt_w(const float* __restrict__ We0, const float* __restrict__ Wa,
                      const float* __restrict__ Wb, const float* __restrict__ tw,
                      _Float16* __restrict__ wt) {
  int i = blockIdx.x * 256 + threadIdx.x;
  if (i < 8192) {
    int n = i >> 7, k = i & 127;
    wt[i] = (_Float16)We0[k * 64 + n];
  } else if (i < 16384) {
    int i2 = i - 8192, j = i2 >> 12, n = (i2 >> 6) & 63, k = i2 & 63;
    wt[i] = (_Float16)Wa[j * 4096 + k * 64 + n];
  } else if (i < 24576) {
    int i2 = i - 16384, j = i2 >> 12, n = (i2 >> 6) & 63, k = i2 & 63;
    wt[i] = (_Float16)Wb[j * 4096 + k * 64 + n];
  } else if (i < 106496) {
    int i2 = i - 24576;
    int p = i2 >> 12, n = (i2 >> 6) & 63, kk = i2 & 63;
    wt[i] = (_Float16)tw[p * 4096 + kk * 64 + n];
  }
}

// ====== CSR propagation: 16 lanes/node = 2 edge-lanes x 8 channel-lanes ======
// pme stream loaded NON-TEMPORAL (evict-first) so the 6.4MB feature table
// keeps its L2 residency; shfl pair-reduce at the end.
__global__ void prop16s(const int* __restrict__ rowptr, const int2* __restrict__ pme,
                        const _Float16* __restrict__ h, _Float16* __restrict__ hn) {
  int idx = blockIdx.x * 256 + threadIdx.x;
  if (idx >= NN * 16) return;
  int n = idx >> 4;
  int sub = idx & 15, el = sub >> 3, q = sub & 7;
  int s = n ? rowptr[n - 1] : 0;
  int epos = rowptr[n];
  const _Float16* hq = h + q * 8;
  const unsigned long long* pml = (const unsigned long long*)pme;
  float a[8];
#pragma unroll
  for (int i = 0; i < 8; i++) a[i] = 0.f;
  int j = s + el;
  for (; j + 6 < epos; j += 8) {
    unsigned long long v0 = __builtin_nontemporal_load(&pml[j]);
    unsigned long long v1 = __builtin_nontemporal_load(&pml[j + 2]);
    unsigned long long v2 = __builtin_nontemporal_load(&pml[j + 4]);
    unsigned long long v3 = __builtin_nontemporal_load(&pml[j + 6]);
    int s0 = (int)(unsigned)v0, s1 = (int)(unsigned)v1;
    int s2 = (int)(unsigned)v2, s3 = (int)(unsigned)v3;
    half8 u0 = *(const half8*)&hq[(size_t)s0 * 64];
    half8 u1 = *(const half8*)&hq[(size_t)s1 * 64];
    half8 u2 = *(const half8*)&hq[(size_t)s2 * 64];
    half8 u3 = *(const half8*)&hq[(size_t)s3 * 64];
    float w0 = __int_as_float((int)(v0 >> 32)), w1 = __int_as_float((int)(v1 >> 32));
    float w2 = __int_as_float((int)(v2 >> 32)), w3 = __int_as_float((int)(v3 >> 32));
#pragma unroll
    for (int i = 0; i < 8; i++)
      a[i] += w0 * (float)u0[i] + w1 * (float)u1[i] + w2 * (float)u2[i] + w3 * (float)u3[i];
  }
  for (; j < epos; j += 2) {
    unsigned long long v = __builtin_nontemporal_load(&pml[j]);
    int sx = (int)(unsigned)v;
    float w = __int_as_float((int)(v >> 32));
    half8 u = *(const half8*)&hq[(size_t)sx * 64];
#pragma unroll
    for (int i = 0; i < 8; i++) a[i] += w * (float)u[i];
  }
#pragma unroll
  for (int i = 0; i < 8; i++) a[i] += __shfl_xor(a[i], 8);
  if (el == 0) {
    half8 o;
#pragma unroll
    for (int i = 0; i < 8; i++) o[i] = (_Float16)a[i];
    *(half8*)&hn[(size_t)n * 64 + q * 8] = o;
  }
}

// 2-channel f32 variant for TAGConv0: 4 edge-lanes/node + shfl reduce
__global__ void prop2s(const int* __restrict__ rowptr, const int2* __restrict__ pme,
                       const float* __restrict__ h, float* __restrict__ hn) {
  int idx = blockIdx.x * 256 + threadIdx.x;
  if (idx >= NN * 4) return;
  int n = idx >> 2, el = idx & 3;
  int s = n ? rowptr[n - 1] : 0;
  int epos = rowptr[n];
  const unsigned long long* pml = (const unsigned long long*)pme;
  float a0 = 0.f, a1 = 0.f;
  for (int j = s + el; j < epos; j += 4) {
    unsigned long long v = __builtin_nontemporal_load(&pml[j]);
    int sx = (int)(unsigned)v;
    float w = __int_as_float((int)(v >> 32));
    a0 += w * h[sx * 2 + 0];
    a1 += w * h[sx * 2 + 1];
  }
  a0 += __shfl_xor(a0, 1); a1 += __shfl_xor(a1, 1);
  a0 += __shfl_xor(a0, 2); a1 += __shfl_xor(a1, 2);
  if (el == 0) {
    hn[n * 2 + 0] = a0;
    hn[n * 2 + 1] = a1;
  }
}

// ================= batched node GEMM (MFMA) with fused epilogue =================
__global__ void __launch_bounds__(128, 4) gemmB_mfma(
    const _Float16* __restrict__ h0, const _Float16* __restrict__ h1,
    const _Float16* __restrict__ h2, const _Float16* __restrict__ h3,
    const _Float16* __restrict__ WT16,  // [4][64][64] f16 pre-transposed
    float* __restrict__ accG, const float* __restrict__ bias,
    const float* __restrict__ residF, _Float16* __restrict__ out16,
    float* __restrict__ st) {
  __shared__ __align__(16) _Float16 hA[128 * HA_STRIDE];
  __shared__ __align__(16) _Float16 WT[64 * WB_STRIDE];
  const int t = threadIdx.x;
  const int lane = t & 63, wv = t >> 6;
  const int a = lane & 15, g = lane >> 4;
  const int nb = blockIdx.x * 128;
  const _Float16* hs[4] = {h0, h1, h2, h3};

  f32x4 acc[4][4];
#pragma unroll
  for (int ct = 0; ct < 4; ct++)
#pragma unroll
    for (int nt = 0; nt < 4; nt++) acc[ct][nt] = (f32x4)0.f;

#pragma unroll 1
  for (int k = 0; k < 4; k++) {
    const _Float16* hk = hs[k];
    {
      size_t base = (size_t)(nb + t) * 64;
#pragma unroll
      for (int i = 0; i < 8; i++)
        *(half8*)&hA[t * HA_STRIDE + i * 8] = *(const half8*)&hk[base + i * 8];
    }
    {
      const _Float16* Wk = WT16 + k * 4096;
      int n = t >> 1, c0 = (t & 1) * 32;
#pragma unroll
      for (int u = 0; u < 4; u++)
        *(half8*)&WT[n * WB_STRIDE + c0 + u * 8] = *(const half8*)&Wk[n * 64 + c0 + u * 8];
    }
    __syncthreads();
#pragma unroll
    for (int ks = 0; ks < 2; ks++) {
      half8 wf[4], hf[4];
#pragma unroll
      for (int nt = 0; nt < 4; nt++)
        wf[nt] = *(const half8*)&WT[(nt * 16 + a) * WB_STRIDE + ks * 32 + g * 8];
#pragma unroll
      for (int ct = 0; ct < 4; ct++)
        hf[ct] = *(const half8*)&hA[(wv * 64 + ct * 16 + a) * HA_STRIDE + ks * 32 + g * 8];
#pragma unroll
      for (int ct = 0; ct < 4; ct++)
#pragma unroll
        for (int nt = 0; nt < 4; nt++)
          acc[ct][nt] = __builtin_amdgcn_mfma_f32_16x16x32_f16(wf[nt], hf[ct], acc[ct][nt], 0, 0, 0);
    }
    __syncthreads();
  }

  if (st) {
    f32x4 ps[4], pss[4];
#pragma unroll
    for (int nt = 0; nt < 4; nt++) { ps[nt] = (f32x4)0.f; pss[nt] = (f32x4)0.f; }
#pragma unroll
    for (int ct = 0; ct < 4; ct++) {
      int node = nb + wv * 64 + ct * 16 + a;
      if (node < NN) {
#pragma unroll
        for (int nt = 0; nt < 4; nt++) {
          ps[nt] += acc[ct][nt];
          pss[nt] += acc[ct][nt] * acc[ct][nt];
        }
      }
    }
#pragma unroll
    for (int o = 1; o < 16; o <<= 1) {
#pragma unroll
      for (int nt = 0; nt < 4; nt++)
#pragma unroll
        for (int r = 0; r < 4; r++) {
          ps[nt][r] += __shfl_xor(ps[nt][r], o);
          pss[nt][r] += __shfl_xor(pss[nt][r], o);
        }
    }
    if (a == 0) {
#pragma unroll
      for (int nt = 0; nt < 4; nt++)
#pragma unroll
        for (int r = 0; r < 4; r++) {
          unsafeAtomicAdd(&st[nt * 16 + g * 4 + r], ps[nt][r]);
          unsafeAtomicAdd(&st[64 + nt * 16 + g * 4 + r], pss[nt][r]);
        }
    }
  }

  f32x4 bias4[4];
  if (bias) {
#pragma unroll
    for (int nt = 0; nt < 4; nt++) bias4[nt] = *(const f32x4*)&bias[nt * 16 + g * 4];
  }
#pragma unroll
  for (int ct = 0; ct < 4; ct++) {
    int node = nb + wv * 64 + ct * 16 + a;
    if (node >= NN) continue;
    if (accG) {
#pragma unroll
      for (int nt = 0; nt < 4; nt++)
        *(f32x4*)&accG[(size_t)node * 64 + nt * 16 + g * 4] = acc[ct][nt];
    }
    if (out16) {
#pragma unroll
      for (int nt = 0; nt < 4; nt++) {
        f32x4 v = acc[ct][nt] + bias4[nt];
        if (residF) v += *(const f32x4*)&residF[(size_t)node * 64 + nt * 16 + g * 4];
        half4v hh = {(_Float16)fmaxf(v[0], 0.f), (_Float16)fmaxf(v[1], 0.f),
                     (_Float16)fmaxf(v[2], 0.f), (_Float16)fmaxf(v[3], 0.f)};
        *(half4v*)&out16[(size_t)node * 64 + nt * 16 + g * 4] = hh;
      }
    }
  }
}

// fused 4-panel 2-ch GEMM (TAGConv0)
__global__ void gemm2B(const float* __restrict__ x, const float* __restrict__ a1,
                       const float* __restrict__ a2, const float* __restrict__ a3,
                       const float* __restrict__ W, float* __restrict__ acc) {
  int idx = blockIdx.x * 256 + threadIdx.x;
  if (idx >= NN * 16) return;
  int n = idx >> 4, q = idx & 15;
  const float* srcs[4] = {x, a1, a2, a3};
  float4 a = make_float4(0.f, 0.f, 0.f, 0.f);
#pragma unroll
  for (int k = 0; k < 4; k++) {
    float x0 = srcs[k][n * 2], x1 = srcs[k][n * 2 + 1];
    float4 w0 = ((const float4*)(W + k * 128))[q];
    float4 w1 = ((const float4*)(W + k * 128 + 64))[q];
    a.x += x0 * w0.x + x1 * w1.x;
    a.y += x0 * w0.y + x1 * w1.y;
    a.z += x0 * w0.z + x1 * w1.z;
    a.w += x0 * w0.w + x1 * w1.w;
  }
  ((float4*)acc)[idx] = a;
}

// ================= InstanceNorm =================
__global__ void stats64(const float* __restrict__ acc, float* __restrict__ st) {
  int c = threadIdx.x & 63, g = threadIdx.x >> 6;
  float s = 0.f, ss = 0.f;
  for (int n = blockIdx.x * 4 + g; n < NN; n += gridDim.x * 4) {
    float v = acc[n * 64 + c];
    s += v; ss += v * v;
  }
  __shared__ float ls[256], lss[256];
  ls[threadIdx.x] = s; lss[threadIdx.x] = ss;
  __syncthreads();
  if (threadIdx.x < 64) {
    s = ls[threadIdx.x] + ls[threadIdx.x + 64] + ls[threadIdx.x + 128] + ls[threadIdx.x + 192];
    ss = lss[threadIdx.x] + lss[threadIdx.x + 64] + lss[threadIdx.x + 128] + lss[threadIdx.x + 192];
    unsafeAtomicAdd(&st[c], s);
    unsafeAtomicAdd(&st[64 + c], ss);
  }
}

__global__ void apply64(const float* __restrict__ acc, const float* __restrict__ st,
                        const float* __restrict__ resid,
                        float* __restrict__ out32, _Float16* __restrict__ out16) {
  int idx = blockIdx.x * 256 + threadIdx.x;
  if (idx >= NN * 16) return;
  int q = idx & 15;
  int c0 = q * 4;
  const float4 av = ((const float4*)acc)[idx];
  const float invN = 1.f / NN;
  float m0 = st[c0 + 0] * invN, m1 = st[c0 + 1] * invN;
  float m2 = st[c0 + 2] * invN, m3 = st[c0 + 3] * invN;
  float r0 = rsqrtf(st[64 + c0 + 0] * invN - m0 * m0 + EPSf);
  float r1 = rsqrtf(st[64 + c0 + 1] * invN - m1 * m1 + EPSf);
  float r2 = rsqrtf(st[64 + c0 + 2] * invN - m2 * m2 + EPSf);
  float r3 = rsqrtf(st[64 + c0 + 3] * invN - m3 * m3 + EPSf);
  float v0 = (av.x - m0) * r0, v1 = (av.y - m1) * r1;
  float v2 = (av.z - m2) * r2, v3 = (av.w - m3) * r3;
  if (resid) {
    const float4 rv = ((const float4*)resid)[idx];
    v0 += rv.x; v1 += rv.y; v2 += rv.z; v3 += rv.w;
  }
  v0 = fmaxf(v0, 0.f); v1 = fmaxf(v1, 0.f);
  v2 = fmaxf(v2, 0.f); v3 = fmaxf(v3, 0.f);
  if (out32) ((float4*)out32)[idx] = make_float4(v0, v1, v2, v3);
  if (out16) {
    half4v hh = {(_Float16)v0, (_Float16)v1, (_Float16)v2, (_Float16)v3};
    *(half4v*)&out16[(size_t)idx * 4] = hh;
  }
}

// ================= MFMA edge MLP (W staged LDS from f16) =================
__device__ __forceinline__ void gstep(f32x4 (&acc)[4][4], const _Float16* hAp,
                                      const _Float16* WTp, int wv, int a, int g) {
#pragma unroll
  for (int ks = 0; ks < 2; ks++) {
    half8 wf[4], hf[4];
#pragma unroll
    for (int nt = 0; nt < 4; nt++)
      wf[nt] = *(const half8*)&WTp[(nt * 16 + a) * WB_STRIDE + ks * 32 + g * 8];
#pragma unroll
    for (int ct = 0; ct < 4; ct++)
      hf[ct] = *(const half8*)&hAp[(wv * 64 + ct * 16 + a) * HA_STRIDE + ks * 32 + g * 8];
#pragma unroll
    for (int ct = 0; ct < 4; ct++)
#pragma unroll
      for (int nt = 0; nt < 4; nt++)
        acc[ct][nt] = __builtin_amdgcn_mfma_f32_16x16x32_f16(wf[nt], hf[ct], acc[ct][nt], 0, 0, 0);
  }
}

__global__ void __launch_bounds__(256, 3) edge_mlp_mfma(
    const _Float16* __restrict__ dat16, const int* __restrict__ row, const int* __restrict__ col,
    const float* __restrict__ ew, const _Float16* __restrict__ wt16,
    const float* __restrict__ We0, const float* __restrict__ be0,
    const float* __restrict__ g0, const float* __restrict__ b0,
    const float* __restrict__ ba, const float* __restrict__ bb,
    const float* __restrict__ lg, const float* __restrict__ lb,
    const float* __restrict__ Wf, const float* __restrict__ bfp,
    float* __restrict__ eout) {
  __shared__ __align__(16) _Float16 hA[256 * HA_STRIDE];
  __shared__ __align__(16) _Float16 WT[64 * WB_STRIDE];
  const _Float16* wt0 = wt16;
  const _Float16* wtA = wt16 + 8192;
  const _Float16* wtB = wt16 + 16384;

  const int t = threadIdx.x;
  const int lane = t & 63, wv = t >> 6;
  const int a = lane & 15, g = lane >> 4;
  const int eb = blockIdx.x * 256;

  auto stageW = [&](const _Float16* src, int stride, int koff) {
    int n = t >> 2, c0 = (t & 3) * 16;
    *(half8*)&WT[n * WB_STRIDE + c0] = *(const half8*)&src[n * stride + koff + c0];
    *(half8*)&WT[n * WB_STRIDE + c0 + 8] = *(const half8*)&src[n * stride + koff + c0 + 8];
  };
  auto stageH = [&](int node) {
    const _Float16* srcp = dat16 + (size_t)node * 64;
#pragma unroll
    for (int i = 0; i < 8; i++)
      *(half8*)&hA[t * HA_STRIDE + i * 8] = *(const half8*)&srcp[i * 8];
  };

  stageH(row[eb + t]);
  stageW(wt0, 128, 0);

  f32x4 be0v[4], w128v[4], g0v[4], b0v[4];
#pragma unroll
  for (int nt = 0; nt < 4; nt++) {
    int ch = nt * 16 + g * 4;
    be0v[nt] = *(const f32x4*)&be0[ch];
    w128v[nt] = *(const f32x4*)&We0[128 * 64 + ch];
    g0v[nt] = *(const f32x4*)&g0[ch];
    b0v[nt] = *(const f32x4*)&b0[ch];
  }

  f32x4 acc[4][4];
#pragma unroll
  for (int ct = 0; ct < 4; ct++) {
    float we = ew[eb + wv * 64 + ct * 16 + a];
#pragma unroll
    for (int nt = 0; nt < 4; nt++) acc[ct][nt] = be0v[nt] + we * w128v[nt];
  }
  __syncthreads();
  gstep(acc, hA, WT, wv, a, g);
  __syncthreads();
  stageH(col[eb + t]);
  stageW(wt0, 128, 64);
  __syncthreads();
  gstep(acc, hA, WT, wv, a, g);

  f32x4 h[4][4];
#pragma unroll
  for (int ct = 0; ct < 4; ct++) {
    float s = 0.f, ss = 0.f;
#pragma unroll
    for (int nt = 0; nt < 4; nt++)
#pragma unroll
      for (int r = 0; r < 4; r++) { float v = acc[ct][nt][r]; s += v; ss += v * v; }
    s += __shfl_xor(s, 16); ss += __shfl_xor(ss, 16);
    s += __shfl_xor(s, 32); ss += __shfl_xor(ss, 32);
    float m = s * (1.f / 64);
    float is = rsqrtf(ss * (1.f / 64) - m * m + EPSf);
#pragma unroll
    for (int nt = 0; nt < 4; nt++)
#pragma unroll
      for (int r = 0; r < 4; r++)
        h[ct][nt][r] = fmaxf((acc[ct][nt][r] - m) * is * g0v[nt][r] + b0v[nt][r], 0.f);
  }
  __syncthreads();

#pragma unroll 1
  for (int j = 0; j < 2; j++) {
#pragma unroll
    for (int ct = 0; ct < 4; ct++)
#pragma unroll
      for (int nt = 0; nt < 4; nt++) {
        half4v hh = {(_Float16)h[ct][nt][0], (_Float16)h[ct][nt][1],
                     (_Float16)h[ct][nt][2], (_Float16)h[ct][nt][3]};
        *(half4v*)&hA[(wv * 64 + ct * 16 + a) * HA_STRIDE + nt * 16 + g * 4] = hh;
      }
    stageW(wtA + j * 4096, 64, 0);
    __syncthreads();
    f32x4 accT[4][4];
#pragma unroll
    for (int nt = 0; nt < 4; nt++) {
      f32x4 bv = *(const f32x4*)&ba[j * 64 + nt * 16 + g * 4];
#pragma unroll
      for (int ct = 0; ct < 4; ct++) accT[ct][nt] = bv;
    }
    gstep(accT, hA, WT, wv, a, g);
    __syncthreads();
#pragma unroll
    for (int ct = 0; ct < 4; ct++)
#pragma unroll
      for (int nt = 0; nt < 4; nt++) {
        half4v hh = {(_Float16)fmaxf(accT[ct][nt][0], 0.f), (_Float16)fmaxf(accT[ct][nt][1], 0.f),
                     (_Float16)fmaxf(accT[ct][nt][2], 0.f), (_Float16)fmaxf(accT[ct][nt][3], 0.f)};
        *(half4v*)&hA[(wv * 64 + ct * 16 + a) * HA_STRIDE + nt * 16 + g * 4] = hh;
      }
    stageW(wtB + j * 4096, 64, 0);
    __syncthreads();
    f32x4 accB[4][4];
#pragma unroll
    for (int nt = 0; nt < 4; nt++) {
      f32x4 bv = *(const f32x4*)&bb[j * 64 + nt * 16 + g * 4];
#pragma unroll
      for (int ct = 0; ct < 4; ct++) accB[ct][nt] = bv;
    }
    gstep(accB, hA, WT, wv, a, g);

    f32x4 lgv[4], lbv[4];
#pragma unroll
    for (int nt = 0; nt < 4; nt++) {
      lgv[nt] = *(const f32x4*)&lg[j * 64 + nt * 16 + g * 4];
      lbv[nt] = *(const f32x4*)&lb[j * 64 + nt * 16 + g * 4];
    }
#pragma unroll
    for (int ct = 0; ct < 4; ct++) {
      float s = 0.f, ss = 0.f;
#pragma unroll
      for (int nt = 0; nt < 4; nt++)
#pragma unroll
        for (int r = 0; r < 4; r++) { float v = accB[ct][nt][r]; s += v; ss += v * v; }
      s += __shfl_xor(s, 16); ss += __shfl_xor(ss, 16);
      s += __shfl_xor(s, 32); ss += __shfl_xor(ss, 32);
      float m = s * (1.f / 64);
      float is = rsqrtf(ss * (1.f / 64) - m * m + EPSf);
#pragma unroll
      for (int nt = 0; nt < 4; nt++)
#pragma unroll
        for (int r = 0; r < 4; r++)
          h[ct][nt][r] =
              fmaxf((accB[ct][nt][r] - m) * is * lgv[nt][r] + lbv[nt][r] + h[ct][nt][r], 0.f);
    }
    __syncthreads();
  }

  f32x4 wfv[4];
#pragma unroll
  for (int nt = 0; nt < 4; nt++) wfv[nt] = *(const f32x4*)&Wf[nt * 16 + g * 4];
  float p0 = 0.f, p1 = 0.f, p2 = 0.f, p3 = 0.f;
#pragma unroll
  for (int nt = 0; nt < 4; nt++)
#pragma unroll
    for (int r = 0; r < 4; r++) {
      p0 += h[0][nt][r] * wfv[nt][r];
      p1 += h[1][nt][r] * wfv[nt][r];
      p2 += h[2][nt][r] * wfv[nt][r];
      p3 += h[3][nt][r] * wfv[nt][r];
    }
  p0 += __shfl_xor(p0, 16); p0 += __shfl_xor(p0, 32);
  p1 += __shfl_xor(p1, 16); p1 += __shfl_xor(p1, 32);
  p2 += __shfl_xor(p2, 16); p2 += __shfl_xor(p2, 32);
  p3 += __shfl_xor(p3, 16); p3 += __shfl_xor(p3, 32);
  float sel = (g == 0) ? p0 : (g == 1) ? p1 : (g == 2) ? p2 : p3;
  eout[eb + t] = sel + bfp[0];
}

// ================= output standardization =================
__global__ void reduce2(const float* __restrict__ v, float* __restrict__ est) {
  __shared__ float ls[256], lss[256];
  float s = 0.f, ss = 0.f;
  for (int i = blockIdx.x * 256 + threadIdx.x; i < NE; i += gridDim.x * 256) {
    float a = v[i]; s += a; ss += a * a;
  }
  ls[threadIdx.x] = s; lss[threadIdx.x] = ss;
  __syncthreads();
  for (int o = 128; o > 0; o >>= 1) {
    if (threadIdx.x < o) { ls[threadIdx.x] += ls[threadIdx.x + o]; lss[threadIdx.x] += lss[threadIdx.x + o]; }
    __syncthreads();
  }
  if (threadIdx.x == 0) {
    unsafeAtomicAdd(&est[0], ls[0]);
    unsafeAtomicAdd(&est[1], lss[0]);
  }
}

__global__ void finalize(const float* __restrict__ eo, const float* __restrict__ est,
                         float* __restrict__ out) {
  int e = blockIdx.x * 256 + threadIdx.x;
  if (e >= NE) return;
  float sum = est[0], ssq = est[1];
  float m = sum * (1.f / NE);
  float var = (ssq - sum * sum * (1.f / NE)) * (1.f / (NE - 1));
  out[e] = fabsf((eo[e] - m) * rsqrtf(var));
}

// ================= host orchestration =================
extern "C" void kernel_launch(void* const* d_in, const int* in_sizes, int n_in,
                              void* d_out, int out_size, void* d_ws, size_t ws_size,
                              hipStream_t stream) {
  const float* x   = (const float*)d_in[0];
  const int*   ei  = (const int*)d_in[1];
  const float* ew  = (const float*)d_in[2];
  const float* t0w = (const float*)d_in[3];
  const float* tw  = (const float*)d_in[5];
  const float* tb  = (const float*)d_in[6];
  const float* We0 = (const float*)d_in[7];
  const float* be0 = (const float*)d_in[8];
  const float* g0  = (const float*)d_in[9];
  const float* b0  = (const float*)d_in[10];
  const float* Wa  = (const float*)d_in[11];
  const float* ba  = (const float*)d_in[12];
  const float* Wb  = (const float*)d_in[13];
  const float* bb  = (const float*)d_in[14];
  const float* lg  = (const float*)d_in[15];
  const float* lb  = (const float*)d_in[16];
  const float* Wf  = (const float*)d_in[17];
  const float* bf  = (const float*)d_in[18];
  const int* row = ei;
  const int* col = ei + NE;

  float* ws = (float*)d_ws;
  int*       rowptr = (int*)ws;                        // NN
  int2*      pme    = (int2*)(ws + 50048);             // NE int2
  float*     st     = ws + 1650048;                    // 192
  float*     est    = st + 128;
  float*     acc    = ws + 1650240;                    // NN*64 f32
  float*     dat    = acc + 3200000;                   // NN*64 f32
  _Float16*  cur16  = (_Float16*)(ws + 8050240);       // NN*64 f16
  _Float16*  mid16  = (_Float16*)(ws + 9650240);       // NN*64 f16
  _Float16*  h1     = (_Float16*)(ws + 11250240);      // NN*64 f16
  _Float16*  h2     = (_Float16*)(ws + 12850240);      // NN*64 f16
  _Float16*  h3     = (_Float16*)(ws + 14450240);      // NN*64 f16
  float*     eout   = ws + 16050240;                   // NE f32
  _Float16*  wt16   = (_Float16*)(ws + 16850240);      // 106496 f16
  float*     deg    = ws + 11250240;                   // alias h1 (prep only)
  int*       aux    = (int*)(ws + 12850240);           // alias h2 (prep only)
  float*     b2a    = ws + 14450240;                   // alias h3 (conv0 only)
  float*     b2b    = b2a + 100096;
  float*     b2c    = b2b + 100096;
  _Float16*  wtT    = wt16 + 24576;

  dim3 blk(256);
#define GRID(n) dim3(((n) + 255) / 256)
  const int NB = (NN + 255) / 256;

  // ---- graph prep ----
  hipMemsetAsync(deg, 0, NN * sizeof(float), stream);
  hipMemsetAsync(rowptr, 0, NN * sizeof(int), stream);
  deg_hist_kernel<<<GRID(NE), blk, 0, stream>>>(row, col, ew, deg, rowptr);
  scan1<<<dim3(NB), blk, 0, stream>>>(rowptr, aux);
  scan2<<<dim3(1), blk, 0, stream>>>(aux, NB);
  scan3<<<dim3(NB), blk, 0, stream>>>(rowptr, aux);
  scatter_kernel<<<GRID(NE), blk, 0, stream>>>(row, col, ew, deg, rowptr, pme);
  cvt_w<<<dim3(416), blk, 0, stream>>>(We0, Wa, Wb, tw, wt16);

  // ---- TAGConv 0 (2 -> 64, f32) ----
  prop2s<<<GRID(NN * 4), blk, 0, stream>>>(rowptr, pme, x, b2a);
  prop2s<<<GRID(NN * 4), blk, 0, stream>>>(rowptr, pme, b2a, b2b);
  prop2s<<<GRID(NN * 4), blk, 0, stream>>>(rowptr, pme, b2b, b2c);
  gemm2B<<<GRID(NN * 16), blk, 0, stream>>>(x, b2a, b2b, b2c, t0w, acc);
  hipMemsetAsync(st, 0, 128 * sizeof(float), stream);
  stats64<<<dim3(128), blk, 0, stream>>>(acc, st);
  apply64<<<GRID(NN * 16), blk, 0, stream>>>(acc, st, nullptr, dat, cur16);

  const int GBB = (NN + 127) / 128;
  auto props = [&](const _Float16* src) {
    prop16s<<<GRID(NN * 16), blk, 0, stream>>>(rowptr, pme, src, h1);
    prop16s<<<GRID(NN * 16), blk, 0, stream>>>(rowptr, pme, h1, h2);
    prop16s<<<GRID(NN * 16), blk, 0, stream>>>(rowptr, pme, h2, h3);
  };

  // ---- residual blocks ----
  for (int i = 0; i < 2; i++) {
    props(cur16);
    gemmB_mfma<<<dim3(GBB), dim3(128), 0, stream>>>(
        cur16, h1, h2, h3, wtT + (2 * i) * 16384,
        nullptr, tb + (2 * i) * 64, nullptr, mid16, nullptr);
    props(mid16);
    hipMemsetAsync(st, 0, 128 * sizeof(float), stream);
    gemmB_mfma<<<dim3(GBB), dim3(128), 0, stream>>>(
        mid16, h1, h2, h3, wtT + (2 * i + 1) * 16384,
        acc, nullptr, nullptr, nullptr, st);
    apply64<<<GRID(NN * 16), blk, 0, stream>>>(acc, st, dat, dat, cur16);
  }
  // ---- final tagconv ----
  props(cur16);
  gemmB_mfma<<<dim3(GBB), dim3(128), 0, stream>>>(
      cur16, h1, h2, h3, wtT + 4 * 16384,
      nullptr, tb + 4 * 64, dat, cur16, nullptr);

  // ---- edge MLP ----
  edge_mlp_mfma<<<GRID(NE), blk, 0, stream>>>(cur16, row, col, ew, wt16, We0, be0, g0, b0,
                                              ba, bb, lg, lb, Wf, bf, eout);
  hipMemsetAsync(est, 0, 2 * sizeof(float), stream);
  reduce2<<<dim3(1024), blk, 0, stream>>>(eout, est);
  finalize<<<GRID(NE), blk, 0, stream>>>(eout, est, (float*)d_out);
#undef GRID
}

// Round 12
// 826.364 us; speedup vs baseline: 1.0702x; 1.0702x over previous
//
#include <hip/hip_runtime.h>

#define NN 50000
#define NE 800000
#define EPSf 1e-5f

typedef _Float16 half8 __attribute__((ext_vector_type(8)));
typedef _Float16 half4v __attribute__((ext_vector_type(4)));
typedef float f32x4 __attribute__((ext_vector_type(4)));

#define HA_STRIDE 72    // halves: 64 + 8 pad (144B rows)
#define WB_STRIDE 72    // halves: 64 + 8 pad (one 64x64 W panel)

// ================= graph prep =================
__global__ void deg_hist_kernel(const int* __restrict__ row, const int* __restrict__ col,
                                const float* __restrict__ ew,
                                float* __restrict__ deg, int* __restrict__ cnt) {
  int e = blockIdx.x * 256 + threadIdx.x;
  if (e >= NE) return;
  int c = col[e];
  unsafeAtomicAdd(&deg[c], ew[e]);
  atomicAdd(&cnt[c], 1);
}

__global__ void scan1(int* __restrict__ cnt, int* __restrict__ aux) {
  __shared__ int ls[256];
  int t = threadIdx.x, idx = blockIdx.x * 256 + t;
  int v = (idx < NN) ? cnt[idx] : 0;
  ls[t] = v;
  __syncthreads();
  for (int o = 1; o < 256; o <<= 1) {
    int u = (t >= o) ? ls[t - o] : 0;
    __syncthreads();
    ls[t] += u;
    __syncthreads();
  }
  if (idx < NN) cnt[idx] = ls[t] - v;
  if (t == 255) aux[blockIdx.x] = ls[255];
}

__global__ void scan2(int* __restrict__ aux, int nb) {
  __shared__ int ls[256];
  int t = threadIdx.x;
  int v = (t < nb) ? aux[t] : 0;
  ls[t] = v;
  __syncthreads();
  for (int o = 1; o < 256; o <<= 1) {
    int u = (t >= o) ? ls[t - o] : 0;
    __syncthreads();
    ls[t] += u;
    __syncthreads();
  }
  if (t < nb) aux[t] = ls[t] - v;
}

__global__ void scan3(int* __restrict__ cnt, const int* __restrict__ aux) {
  int idx = blockIdx.x * 256 + threadIdx.x;
  if (idx < NN) cnt[idx] += aux[idx >> 8];
}

// scatter with inline symmetric normalization (dinv folded in)
__global__ void scatter_kernel(const int* __restrict__ row, const int* __restrict__ col,
                               const float* __restrict__ ew, const float* __restrict__ deg,
                               int* __restrict__ rowptr, int2* __restrict__ pme) {
  int e = blockIdx.x * 256 + threadIdx.x;
  if (e >= NE) return;
  int r = row[e], c = col[e];
  float dr = deg[r], dc = deg[c];
  float ir = dr > 0.f ? rsqrtf(dr) : 0.f;
  float ic = dc > 0.f ? rsqrtf(dc) : 0.f;
  float w = ir * ew[e] * ic;
  int p = atomicAdd(&rowptr[c], 1);
  pme[p] = make_int2(r, __float_as_int(w));
}

// convert + transpose ALL MFMA weights to f16 once.
__global__ void cvt_w(const float* __restrict__ We0, const float* __restrict__ Wa,
                      const float* __restrict__ Wb, const float* __restrict__ tw,
                      _Float16* __restrict__ wt) {
  int i = blockIdx.x * 256 + threadIdx.x;
  if (i < 8192) {
    int n = i >> 7, k = i & 127;
    wt[i] = (_Float16)We0[k * 64 + n];
  } else if (i < 16384) {
    int i2 = i - 8192, j = i2 >> 12, n = (i2 >> 6) & 63, k = i2 & 63;
    wt[i] = (_Float16)Wa[j * 4096 + k * 64 + n];
  } else if (i < 24576) {
    int i2 = i - 16384, j = i2 >> 12, n = (i2 >> 6) & 63, k = i2 & 63;
    wt[i] = (_Float16)Wb[j * 4096 + k * 64 + n];
  } else if (i < 106496) {
    int i2 = i - 24576;
    int p = i2 >> 12, n = (i2 >> 6) & 63, kk = i2 & 63;
    wt[i] = (_Float16)tw[p * 4096 + kk * 64 + n];
  }
}

// ====== CSR propagation: 16 lanes/node = 2 edge-lanes x 8 channel-lanes ======
// natural node order (contiguous writes); plain cached loads (NT hurt: R10).
__global__ void prop16s(const int* __restrict__ rowptr, const int2* __restrict__ pme,
                        const _Float16* __restrict__ h, _Float16* __restrict__ hn) {
  int idx = blockIdx.x * 256 + threadIdx.x;
  if (idx >= NN * 16) return;
  int n = idx >> 4;
  int sub = idx & 15, el = sub >> 3, q = sub & 7;
  int s = n ? rowptr[n - 1] : 0;
  int epos = rowptr[n];
  const _Float16* hq = h + q * 8;
  float a[8];
#pragma unroll
  for (int i = 0; i < 8; i++) a[i] = 0.f;
  int j = s + el;
  for (; j + 6 < epos; j += 8) {
    int2 m0 = pme[j], m1 = pme[j + 2], m2 = pme[j + 4], m3 = pme[j + 6];
    half8 u0 = *(const half8*)&hq[(size_t)m0.x * 64];
    half8 u1 = *(const half8*)&hq[(size_t)m1.x * 64];
    half8 u2 = *(const half8*)&hq[(size_t)m2.x * 64];
    half8 u3 = *(const half8*)&hq[(size_t)m3.x * 64];
    float w0 = __int_as_float(m0.y), w1 = __int_as_float(m1.y);
    float w2 = __int_as_float(m2.y), w3 = __int_as_float(m3.y);
#pragma unroll
    for (int i = 0; i < 8; i++)
      a[i] += w0 * (float)u0[i] + w1 * (float)u1[i] + w2 * (float)u2[i] + w3 * (float)u3[i];
  }
  for (; j < epos; j += 2) {
    int2 m = pme[j];
    float w = __int_as_float(m.y);
    half8 u = *(const half8*)&hq[(size_t)m.x * 64];
#pragma unroll
    for (int i = 0; i < 8; i++) a[i] += w * (float)u[i];
  }
#pragma unroll
  for (int i = 0; i < 8; i++) a[i] += __shfl_xor(a[i], 8);
  if (el == 0) {
    half8 o;
#pragma unroll
    for (int i = 0; i < 8; i++) o[i] = (_Float16)a[i];
    *(half8*)&hn[(size_t)n * 64 + q * 8] = o;
  }
}

// 2-channel f32 variant for TAGConv0: 4 edge-lanes/node + shfl reduce
__global__ void prop2s(const int* __restrict__ rowptr, const int2* __restrict__ pme,
                       const float* __restrict__ h, float* __restrict__ hn) {
  int idx = blockIdx.x * 256 + threadIdx.x;
  if (idx >= NN * 4) return;
  int n = idx >> 2, el = idx & 3;
  int s = n ? rowptr[n - 1] : 0;
  int epos = rowptr[n];
  float a0 = 0.f, a1 = 0.f;
  for (int j = s + el; j < epos; j += 4) {
    int2 m = pme[j];
    float w = __int_as_float(m.y);
    a0 += w * h[m.x * 2 + 0];
    a1 += w * h[m.x * 2 + 1];
  }
  a0 += __shfl_xor(a0, 1); a1 += __shfl_xor(a1, 1);
  a0 += __shfl_xor(a0, 2); a1 += __shfl_xor(a1, 2);
  if (el == 0) {
    hn[n * 2 + 0] = a0;
    hn[n * 2 + 1] = a1;
  }
}

// ================= batched node GEMM (MFMA) with fused epilogue =================
__global__ void __launch_bounds__(128, 4) gemmB_mfma(
    const _Float16* __restrict__ h0, const _Float16* __restrict__ h1,
    const _Float16* __restrict__ h2, const _Float16* __restrict__ h3,
    const _Float16* __restrict__ WT16,  // [4][64][64] f16 pre-transposed
    float* __restrict__ accG, const float* __restrict__ bias,
    const float* __restrict__ residF, _Float16* __restrict__ out16,
    float* __restrict__ st) {
  __shared__ __align__(16) _Float16 hA[128 * HA_STRIDE];
  __shared__ __align__(16) _Float16 WT[64 * WB_STRIDE];
  const int t = threadIdx.x;
  const int lane = t & 63, wv = t >> 6;
  const int a = lane & 15, g = lane >> 4;
  const int nb = blockIdx.x * 128;
  const _Float16* hs[4] = {h0, h1, h2, h3};

  f32x4 acc[4][4];
#pragma unroll
  for (int ct = 0; ct < 4; ct++)
#pragma unroll
    for (int nt = 0; nt < 4; nt++) acc[ct][nt] = (f32x4)0.f;

#pragma unroll 1
  for (int k = 0; k < 4; k++) {
    const _Float16* hk = hs[k];
    {
      size_t base = (size_t)(nb + t) * 64;
#pragma unroll
      for (int i = 0; i < 8; i++)
        *(half8*)&hA[t * HA_STRIDE + i * 8] = *(const half8*)&hk[base + i * 8];
    }
    {
      const _Float16* Wk = WT16 + k * 4096;
      int n = t >> 1, c0 = (t & 1) * 32;
#pragma unroll
      for (int u = 0; u < 4; u++)
        *(half8*)&WT[n * WB_STRIDE + c0 + u * 8] = *(const half8*)&Wk[n * 64 + c0 + u * 8];
    }
    __syncthreads();
#pragma unroll
    for (int ks = 0; ks < 2; ks++) {
      half8 wf[4], hf[4];
#pragma unroll
      for (int nt = 0; nt < 4; nt++)
        wf[nt] = *(const half8*)&WT[(nt * 16 + a) * WB_STRIDE + ks * 32 + g * 8];
#pragma unroll
      for (int ct = 0; ct < 4; ct++)
        hf[ct] = *(const half8*)&hA[(wv * 64 + ct * 16 + a) * HA_STRIDE + ks * 32 + g * 8];
#pragma unroll
      for (int ct = 0; ct < 4; ct++)
#pragma unroll
        for (int nt = 0; nt < 4; nt++)
          acc[ct][nt] = __builtin_amdgcn_mfma_f32_16x16x32_f16(wf[nt], hf[ct], acc[ct][nt], 0, 0, 0);
    }
    __syncthreads();
  }

  if (st) {
    f32x4 ps[4], pss[4];
#pragma unroll
    for (int nt = 0; nt < 4; nt++) { ps[nt] = (f32x4)0.f; pss[nt] = (f32x4)0.f; }
#pragma unroll
    for (int ct = 0; ct < 4; ct++) {
      int node = nb + wv * 64 + ct * 16 + a;
      if (node < NN) {
#pragma unroll
        for (int nt = 0; nt < 4; nt++) {
          ps[nt] += acc[ct][nt];
          pss[nt] += acc[ct][nt] * acc[ct][nt];
        }
      }
    }
#pragma unroll
    for (int o = 1; o < 16; o <<= 1) {
#pragma unroll
      for (int nt = 0; nt < 4; nt++)
#pragma unroll
        for (int r = 0; r < 4; r++) {
          ps[nt][r] += __shfl_xor(ps[nt][r], o);
          pss[nt][r] += __shfl_xor(pss[nt][r], o);
        }
    }
    if (a == 0) {
#pragma unroll
      for (int nt = 0; nt < 4; nt++)
#pragma unroll
        for (int r = 0; r < 4; r++) {
          unsafeAtomicAdd(&st[nt * 16 + g * 4 + r], ps[nt][r]);
          unsafeAtomicAdd(&st[64 + nt * 16 + g * 4 + r], pss[nt][r]);
        }
    }
  }

  f32x4 bias4[4];
  if (bias) {
#pragma unroll
    for (int nt = 0; nt < 4; nt++) bias4[nt] = *(const f32x4*)&bias[nt * 16 + g * 4];
  }
#pragma unroll
  for (int ct = 0; ct < 4; ct++) {
    int node = nb + wv * 64 + ct * 16 + a;
    if (node >= NN) continue;
    if (accG) {
#pragma unroll
      for (int nt = 0; nt < 4; nt++)
        *(f32x4*)&accG[(size_t)node * 64 + nt * 16 + g * 4] = acc[ct][nt];
    }
    if (out16) {
#pragma unroll
      for (int nt = 0; nt < 4; nt++) {
        f32x4 v = acc[ct][nt] + bias4[nt];
        if (residF) v += *(const f32x4*)&residF[(size_t)node * 64 + nt * 16 + g * 4];
        half4v hh = {(_Float16)fmaxf(v[0], 0.f), (_Float16)fmaxf(v[1], 0.f),
                     (_Float16)fmaxf(v[2], 0.f), (_Float16)fmaxf(v[3], 0.f)};
        *(half4v*)&out16[(size_t)node * 64 + nt * 16 + g * 4] = hh;
      }
    }
  }
}

// fused 4-panel 2-ch GEMM (TAGConv0)
__global__ void gemm2B(const float* __restrict__ x, const float* __restrict__ a1,
                       const float* __restrict__ a2, const float* __restrict__ a3,
                       const float* __restrict__ W, float* __restrict__ acc) {
  int idx = blockIdx.x * 256 + threadIdx.x;
  if (idx >= NN * 16) return;
  int n = idx >> 4, q = idx & 15;
  const float* srcs[4] = {x, a1, a2, a3};
  float4 a = make_float4(0.f, 0.f, 0.f, 0.f);
#pragma unroll
  for (int k = 0; k < 4; k++) {
    float x0 = srcs[k][n * 2], x1 = srcs[k][n * 2 + 1];
    float4 w0 = ((const float4*)(W + k * 128))[q];
    float4 w1 = ((const float4*)(W + k * 128 + 64))[q];
    a.x += x0 * w0.x + x1 * w1.x;
    a.y += x0 * w0.y + x1 * w1.y;
    a.z += x0 * w0.z + x1 * w1.z;
    a.w += x0 * w0.w + x1 * w1.w;
  }
  ((float4*)acc)[idx] = a;
}

// ================= InstanceNorm =================
__global__ void stats64(const float* __restrict__ acc, float* __restrict__ st) {
  int c = threadIdx.x & 63, g = threadIdx.x >> 6;
  float s = 0.f, ss = 0.f;
  for (int n = blockIdx.x * 4 + g; n < NN; n += gridDim.x * 4) {
    float v = acc[n * 64 + c];
    s += v; ss += v * v;
  }
  __shared__ float ls[256], lss[256];
  ls[threadIdx.x] = s; lss[threadIdx.x] = ss;
  __syncthreads();
  if (threadIdx.x < 64) {
    s = ls[threadIdx.x] + ls[threadIdx.x + 64] + ls[threadIdx.x + 128] + ls[threadIdx.x + 192];
    ss = lss[threadIdx.x] + lss[threadIdx.x + 64] + lss[threadIdx.x + 128] + lss[threadIdx.x + 192];
    unsafeAtomicAdd(&st[c], s);
    unsafeAtomicAdd(&st[64 + c], ss);
  }
}

__global__ void apply64(const float* __restrict__ acc, const float* __restrict__ st,
                        const float* __restrict__ resid,
                        float* __restrict__ out32, _Float16* __restrict__ out16) {
  int idx = blockIdx.x * 256 + threadIdx.x;
  if (idx >= NN * 16) return;
  int q = idx & 15;
  int c0 = q * 4;
  const float4 av = ((const float4*)acc)[idx];
  const float invN = 1.f / NN;
  float m0 = st[c0 + 0] * invN, m1 = st[c0 + 1] * invN;
  float m2 = st[c0 + 2] * invN, m3 = st[c0 + 3] * invN;
  float r0 = rsqrtf(st[64 + c0 + 0] * invN - m0 * m0 + EPSf);
  float r1 = rsqrtf(st[64 + c0 + 1] * invN - m1 * m1 + EPSf);
  float r2 = rsqrtf(st[64 + c0 + 2] * invN - m2 * m2 + EPSf);
  float r3 = rsqrtf(st[64 + c0 + 3] * invN - m3 * m3 + EPSf);
  float v0 = (av.x - m0) * r0, v1 = (av.y - m1) * r1;
  float v2 = (av.z - m2) * r2, v3 = (av.w - m3) * r3;
  if (resid) {
    const float4 rv = ((const float4*)resid)[idx];
    v0 += rv.x; v1 += rv.y; v2 += rv.z; v3 += rv.w;
  }
  v0 = fmaxf(v0, 0.f); v1 = fmaxf(v1, 0.f);
  v2 = fmaxf(v2, 0.f); v3 = fmaxf(v3, 0.f);
  if (out32) ((float4*)out32)[idx] = make_float4(v0, v1, v2, v3);
  if (out16) {
    half4v hh = {(_Float16)v0, (_Float16)v1, (_Float16)v2, (_Float16)v3};
    *(half4v*)&out16[(size_t)idx * 4] = hh;
  }
}

// ================= MFMA edge MLP (W staged LDS from f16) =================
__device__ __forceinline__ void gstep(f32x4 (&acc)[4][4], const _Float16* hAp,
                                      const _Float16* WTp, int wv, int a, int g) {
#pragma unroll
  for (int ks = 0; ks < 2; ks++) {
    half8 wf[4], hf[4];
#pragma unroll
    for (int nt = 0; nt < 4; nt++)
      wf[nt] = *(const half8*)&WTp[(nt * 16 + a) * WB_STRIDE + ks * 32 + g * 8];
#pragma unroll
    for (int ct = 0; ct < 4; ct++)
      hf[ct] = *(const half8*)&hAp[(wv * 64 + ct * 16 + a) * HA_STRIDE + ks * 32 + g * 8];
#pragma unroll
    for (int ct = 0; ct < 4; ct++)
#pragma unroll
      for (int nt = 0; nt < 4; nt++)
        acc[ct][nt] = __builtin_amdgcn_mfma_f32_16x16x32_f16(wf[nt], hf[ct], acc[ct][nt], 0, 0, 0);
  }
}

__global__ void __launch_bounds__(256, 3) edge_mlp_mfma(
    const _Float16* __restrict__ dat16, const int* __restrict__ row, const int* __restrict__ col,
    const float* __restrict__ ew, const _Float16* __restrict__ wt16,
    const float* __restrict__ We0, const float* __restrict__ be0,
    const float* __restrict__ g0, const float* __restrict__ b0,
    const float* __restrict__ ba, const float* __restrict__ bb,
    const float* __restrict__ lg, const float* __restrict__ lb,
    const float* __restrict__ Wf, const float* __restrict__ bfp,
    float* __restrict__ eout, float* __restrict__ est) {
  __shared__ __align__(16) _Float16 hA[256 * HA_STRIDE];
  __shared__ __align__(16) _Float16 WT[64 * WB_STRIDE];
  const _Float16* wt0 = wt16;
  const _Float16* wtA = wt16 + 8192;
  const _Float16* wtB = wt16 + 16384;

  const int t = threadIdx.x;
  const int lane = t & 63, wv = t >> 6;
  const int a = lane & 15, g = lane >> 4;
  const int eb = blockIdx.x * 256;

  auto stageW = [&](const _Float16* src, int stride, int koff) {
    int n = t >> 2, c0 = (t & 3) * 16;
    *(half8*)&WT[n * WB_STRIDE + c0] = *(const half8*)&src[n * stride + koff + c0];
    *(half8*)&WT[n * WB_STRIDE + c0 + 8] = *(const half8*)&src[n * stride + koff + c0 + 8];
  };
  auto stageH = [&](int node) {
    const _Float16* srcp = dat16 + (size_t)node * 64;
#pragma unroll
    for (int i = 0; i < 8; i++)
      *(half8*)&hA[t * HA_STRIDE + i * 8] = *(const half8*)&srcp[i * 8];
  };

  stageH(row[eb + t]);
  stageW(wt0, 128, 0);

  f32x4 be0v[4], w128v[4], g0v[4], b0v[4];
#pragma unroll
  for (int nt = 0; nt < 4; nt++) {
    int ch = nt * 16 + g * 4;
    be0v[nt] = *(const f32x4*)&be0[ch];
    w128v[nt] = *(const f32x4*)&We0[128 * 64 + ch];
    g0v[nt] = *(const f32x4*)&g0[ch];
    b0v[nt] = *(const f32x4*)&b0[ch];
  }

  f32x4 acc[4][4];
#pragma unroll
  for (int ct = 0; ct < 4; ct++) {
    float we = ew[eb + wv * 64 + ct * 16 + a];
#pragma unroll
    for (int nt = 0; nt < 4; nt++) acc[ct][nt] = be0v[nt] + we * w128v[nt];
  }
  __syncthreads();
  gstep(acc, hA, WT, wv, a, g);
  __syncthreads();
  stageH(col[eb + t]);
  stageW(wt0, 128, 64);
  __syncthreads();
  gstep(acc, hA, WT, wv, a, g);

  f32x4 h[4][4];
#pragma unroll
  for (int ct = 0; ct < 4; ct++) {
    float s = 0.f, ss = 0.f;
#pragma unroll
    for (int nt = 0; nt < 4; nt++)
#pragma unroll
      for (int r = 0; r < 4; r++) { float v = acc[ct][nt][r]; s += v; ss += v * v; }
    s += __shfl_xor(s, 16); ss += __shfl_xor(ss, 16);
    s += __shfl_xor(s, 32); ss += __shfl_xor(ss, 32);
    float m = s * (1.f / 64);
    float is = rsqrtf(ss * (1.f / 64) - m * m + EPSf);
#pragma unroll
    for (int nt = 0; nt < 4; nt++)
#pragma unroll
      for (int r = 0; r < 4; r++)
        h[ct][nt][r] = fmaxf((acc[ct][nt][r] - m) * is * g0v[nt][r] + b0v[nt][r], 0.f);
  }
  __syncthreads();

#pragma unroll 1
  for (int j = 0; j < 2; j++) {
#pragma unroll
    for (int ct = 0; ct < 4; ct++)
#pragma unroll
      for (int nt = 0; nt < 4; nt++) {
        half4v hh = {(_Float16)h[ct][nt][0], (_Float16)h[ct][nt][1],
                     (_Float16)h[ct][nt][2], (_Float16)h[ct][nt][3]};
        *(half4v*)&hA[(wv * 64 + ct * 16 + a) * HA_STRIDE + nt * 16 + g * 4] = hh;
      }
    stageW(wtA + j * 4096, 64, 0);
    __syncthreads();
    f32x4 accT[4][4];
#pragma unroll
    for (int nt = 0; nt < 4; nt++) {
      f32x4 bv = *(const f32x4*)&ba[j * 64 + nt * 16 + g * 4];
#pragma unroll
      for (int ct = 0; ct < 4; ct++) accT[ct][nt] = bv;
    }
    gstep(accT, hA, WT, wv, a, g);
    __syncthreads();
#pragma unroll
    for (int ct = 0; ct < 4; ct++)
#pragma unroll
      for (int nt = 0; nt < 4; nt++) {
        half4v hh = {(_Float16)fmaxf(accT[ct][nt][0], 0.f), (_Float16)fmaxf(accT[ct][nt][1], 0.f),
                     (_Float16)fmaxf(accT[ct][nt][2], 0.f), (_Float16)fmaxf(accT[ct][nt][3], 0.f)};
        *(half4v*)&hA[(wv * 64 + ct * 16 + a) * HA_STRIDE + nt * 16 + g * 4] = hh;
      }
    stageW(wtB + j * 4096, 64, 0);
    __syncthreads();
    f32x4 accB[4][4];
#pragma unroll
    for (int nt = 0; nt < 4; nt++) {
      f32x4 bv = *(const f32x4*)&bb[j * 64 + nt * 16 + g * 4];
#pragma unroll
      for (int ct = 0; ct < 4; ct++) accB[ct][nt] = bv;
    }
    gstep(accB, hA, WT, wv, a, g);

    f32x4 lgv[4], lbv[4];
#pragma unroll
    for (int nt = 0; nt < 4; nt++) {
      lgv[nt] = *(const f32x4*)&lg[j * 64 + nt * 16 + g * 4];
      lbv[nt] = *(const f32x4*)&lb[j * 64 + nt * 16 + g * 4];
    }
#pragma unroll
    for (int ct = 0; ct < 4; ct++) {
      float s = 0.f, ss = 0.f;
#pragma unroll
      for (int nt = 0; nt < 4; nt++)
#pragma unroll
        for (int r = 0; r < 4; r++) { float v = accB[ct][nt][r]; s += v; ss += v * v; }
      s += __shfl_xor(s, 16); ss += __shfl_xor(ss, 16);
      s += __shfl_xor(s, 32); ss += __shfl_xor(ss, 32);
      float m = s * (1.f / 64);
      float is = rsqrtf(ss * (1.f / 64) - m * m + EPSf);
#pragma unroll
      for (int nt = 0; nt < 4; nt++)
#pragma unroll
        for (int r = 0; r < 4; r++)
          h[ct][nt][r] =
              fmaxf((accB[ct][nt][r] - m) * is * lgv[nt][r] + lbv[nt][r] + h[ct][nt][r], 0.f);
    }
    __syncthreads();
  }

  f32x4 wfv[4];
#pragma unroll
  for (int nt = 0; nt < 4; nt++) wfv[nt] = *(const f32x4*)&Wf[nt * 16 + g * 4];
  float p0 = 0.f, p1 = 0.f, p2 = 0.f, p3 = 0.f;
#pragma unroll
  for (int nt = 0; nt < 4; nt++)
#pragma unroll
    for (int r = 0; r < 4; r++) {
      p0 += h[0][nt][r] * wfv[nt][r];
      p1 += h[1][nt][r] * wfv[nt][r];
      p2 += h[2][nt][r] * wfv[nt][r];
      p3 += h[3][nt][r] * wfv[nt][r];
    }
  p0 += __shfl_xor(p0, 16); p0 += __shfl_xor(p0, 32);
  p1 += __shfl_xor(p1, 16); p1 += __shfl_xor(p1, 32);
  p2 += __shfl_xor(p2, 16); p2 += __shfl_xor(p2, 32);
  p3 += __shfl_xor(p3, 16); p3 += __shfl_xor(p3, 32);
  float sel = (g == 0) ? p0 : (g == 1) ? p1 : (g == 2) ? p2 : p3;
  float myv = sel + bfp[0];
  eout[eb + t] = myv;

  // ---- fused block reduction for output standardization ----
  __syncthreads();  // all hA reads done
  float* rbuf = (float*)hA;  // reuse LDS: [256] sum, [256] sumsq
  rbuf[t] = myv;
  rbuf[256 + t] = myv * myv;
  __syncthreads();
  for (int o = 128; o > 0; o >>= 1) {
    if (t < o) {
      rbuf[t] += rbuf[t + o];
      rbuf[256 + t] += rbuf[256 + t + o];
    }
    __syncthreads();
  }
  if (t == 0) {
    unsafeAtomicAdd(&est[0], rbuf[0]);
    unsafeAtomicAdd(&est[1], rbuf[256]);
  }
}

// ================= output standardization =================
__global__ void finalize(const float* __restrict__ eo, const float* __restrict__ est,
                         float* __restrict__ out) {
  int e = blockIdx.x * 256 + threadIdx.x;
  if (e >= NE) return;
  float sum = est[0], ssq = est[1];
  float m = sum * (1.f / NE);
  float var = (ssq - sum * sum * (1.f / NE)) * (1.f / (NE - 1));
  out[e] = fabsf((eo[e] - m) * rsqrtf(var));
}

// ================= host orchestration =================
extern "C" void kernel_launch(void* const* d_in, const int* in_sizes, int n_in,
                              void* d_out, int out_size, void* d_ws, size_t ws_size,
                              hipStream_t stream) {
  const float* x   = (const float*)d_in[0];
  const int*   ei  = (const int*)d_in[1];
  const float* ew  = (const float*)d_in[2];
  const float* t0w = (const float*)d_in[3];
  const float* tw  = (const float*)d_in[5];
  const float* tb  = (const float*)d_in[6];
  const float* We0 = (const float*)d_in[7];
  const float* be0 = (const float*)d_in[8];
  const float* g0  = (const float*)d_in[9];
  const float* b0  = (const float*)d_in[10];
  const float* Wa  = (const float*)d_in[11];
  const float* ba  = (const float*)d_in[12];
  const float* Wb  = (const float*)d_in[13];
  const float* bb  = (const float*)d_in[14];
  const float* lg  = (const float*)d_in[15];
  const float* lb  = (const float*)d_in[16];
  const float* Wf  = (const float*)d_in[17];
  const float* bf  = (const float*)d_in[18];
  const int* row = ei;
  const int* col = ei + NE;

  float* ws = (float*)d_ws;
  int*       rowptr = (int*)ws;                        // NN
  int2*      pme    = (int2*)(ws + 50048);             // NE int2
  float*     st     = ws + 1650048;                    // 192
  float*     est    = st + 128;
  float*     acc    = ws + 1650240;                    // NN*64 f32
  float*     dat    = acc + 3200000;                   // NN*64 f32
  _Float16*  cur16  = (_Float16*)(ws + 8050240);       // NN*64 f16
  _Float16*  mid16  = (_Float16*)(ws + 9650240);       // NN*64 f16
  _Float16*  h1     = (_Float16*)(ws + 11250240);      // NN*64 f16
  _Float16*  h2     = (_Float16*)(ws + 12850240);      // NN*64 f16
  _Float16*  h3     = (_Float16*)(ws + 14450240);      // NN*64 f16
  float*     eout   = ws + 16050240;                   // NE f32
  _Float16*  wt16   = (_Float16*)(ws + 16850240);      // 106496 f16
  float*     deg    = ws + 11250240;                   // alias h1 (prep only)
  int*       aux    = (int*)(ws + 12850240);           // alias h2 (prep only)
  float*     b2a    = ws + 14450240;                   // alias h3 (conv0 only)
  float*     b2b    = b2a + 100096;
  float*     b2c    = b2b + 100096;
  _Float16*  wtT    = wt16 + 24576;

  dim3 blk(256);
#define GRID(n) dim3(((n) + 255) / 256)
  const int NB = (NN + 255) / 256;

  // ---- graph prep ----
  hipMemsetAsync(deg, 0, NN * sizeof(float), stream);
  hipMemsetAsync(rowptr, 0, NN * sizeof(int), stream);
  deg_hist_kernel<<<GRID(NE), blk, 0, stream>>>(row, col, ew, deg, rowptr);
  scan1<<<dim3(NB), blk, 0, stream>>>(rowptr, aux);
  scan2<<<dim3(1), blk, 0, stream>>>(aux, NB);
  scan3<<<dim3(NB), blk, 0, stream>>>(rowptr, aux);
  scatter_kernel<<<GRID(NE), blk, 0, stream>>>(row, col, ew, deg, rowptr, pme);
  cvt_w<<<dim3(416), blk, 0, stream>>>(We0, Wa, Wb, tw, wt16);

  // ---- TAGConv 0 (2 -> 64, f32) ----
  prop2s<<<GRID(NN * 4), blk, 0, stream>>>(rowptr, pme, x, b2a);
  prop2s<<<GRID(NN * 4), blk, 0, stream>>>(rowptr, pme, b2a, b2b);
  prop2s<<<GRID(NN * 4), blk, 0, stream>>>(rowptr, pme, b2b, b2c);
  gemm2B<<<GRID(NN * 16), blk, 0, stream>>>(x, b2a, b2b, b2c, t0w, acc);
  hipMemsetAsync(st, 0, 128 * sizeof(float), stream);
  stats64<<<dim3(128), blk, 0, stream>>>(acc, st);
  apply64<<<GRID(NN * 16), blk, 0, stream>>>(acc, st, nullptr, dat, cur16);

  const int GBB = (NN + 127) / 128;
  auto props = [&](const _Float16* src) {
    prop16s<<<GRID(NN * 16), blk, 0, stream>>>(rowptr, pme, src, h1);
    prop16s<<<GRID(NN * 16), blk, 0, stream>>>(rowptr, pme, h1, h2);
    prop16s<<<GRID(NN * 16), blk, 0, stream>>>(rowptr, pme, h2, h3);
  };

  // ---- residual blocks ----
  for (int i = 0; i < 2; i++) {
    props(cur16);
    gemmB_mfma<<<dim3(GBB), dim3(128), 0, stream>>>(
        cur16, h1, h2, h3, wtT + (2 * i) * 16384,
        nullptr, tb + (2 * i) * 64, nullptr, mid16, nullptr);
    props(mid16);
    hipMemsetAsync(st, 0, 128 * sizeof(float), stream);
    gemmB_mfma<<<dim3(GBB), dim3(128), 0, stream>>>(
        mid16, h1, h2, h3, wtT + (2 * i + 1) * 16384,
        acc, nullptr, nullptr, nullptr, st);
    apply64<<<GRID(NN * 16), blk, 0, stream>>>(acc, st, dat, dat, cur16);
  }
  // ---- final tagconv ----
  props(cur16);
  gemmB_mfma<<<dim3(GBB), dim3(128), 0, stream>>>(
      cur16, h1, h2, h3, wtT + 4 * 16384,
      nullptr, tb + 4 * 64, dat, cur16, nullptr);

  // ---- edge MLP with fused output-stats reduction ----
  hipMemsetAsync(est, 0, 2 * sizeof(float), stream);
  edge_mlp_mfma<<<GRID(NE), blk, 0, stream>>>(cur16, row, col, ew, wt16, We0, be0, g0, b0,
                                              ba, bb, lg, lb, Wf, bf, eout, est);
  finalize<<<GRID(NE), blk, 0, stream>>>(eout, est, (float*)d_out);
#undef GRID
}